// Round 3
// baseline (63.254 us; speedup 1.0000x reference)
//
#include <hip/hip_runtime.h>

// B=32, C=1, H=W=112, O=64, KH=KW=5, stride=1 -> oh=ow=108
constexpr int KH = 5, KW = 5;
constexpr int O  = 64;
constexpr int D  = KH * KW;          // 25
constexpr int H  = 112, W = 112;
constexpr int OH = H - KH + 1;       // 108
constexpr int OW = W - KW + 1;       // 108
constexpr int P  = OH * OW;          // 11664

// d_ws layout (floats): wTg[25][64] | wTr[25][64] | n2g[64] | n2r[64]
constexpr int WS_FLOATS = 2 * D * O + 2 * O;   // 3328 floats = 13,312 B

__global__ void prep_weights(const float* __restrict__ gw,
                             const float* __restrict__ rw,
                             float* __restrict__ ws) {
    const int o = threadIdx.x;
    if (o >= O) return;
    float sg = 0.f, sr = 0.f;
    #pragma unroll
    for (int k = 0; k < D; ++k) {
        float a = gw[o * D + k]; ws[k * O + o]       = a; sg = fmaf(a, a, sg);
        float b = rw[o * D + k]; ws[(D + k) * O + o] = b; sr = fmaf(b, b, sr);
    }
    ws[2 * D * O + o]     = sg;
    ws[2 * D * O + O + o] = sr;
}

__global__ __launch_bounds__(256, 4) void rbf_main(
    const float* __restrict__ gin, const float* __restrict__ rin,
    const float* __restrict__ ws,  const float* __restrict__ stdp,
    float* __restrict__ out, int B)
{
    const int idx = blockIdx.x * 256 + threadIdx.x;
    if (idx >= B * P) return;
    const int b = idx / P;
    const int p = idx - b * P;
    const int y = p / OW;
    const int x = p - y * OW;

    const float* gb = gin + (b * H + y) * W + x;
    const float* rb = rin + (b * H + y) * W + x;

    // Load the 5x5 patches into registers ONCE.
    float ga[D], ra[D];
    #pragma unroll
    for (int i = 0; i < KH; ++i) {
        #pragma unroll
        for (int j = 0; j < KW; ++j) {
            ga[i * KW + j] = gb[i * W + j];
            ra[i * KW + j] = rb[i * W + j];
        }
    }
    // PIN in VGPRs: make values opaque so the compiler cannot re-materialize
    // them by re-loading from (read-only) global inside the channel loop.
    #pragma unroll
    for (int k = 0; k < D; ++k) {
        asm volatile("" : "+v"(ga[k]), "+v"(ra[k]));
    }

    float a2g = 0.f, a2r = 0.f;
    #pragma unroll
    for (int k = 0; k < D; ++k) {
        a2g = fmaf(ga[k], ga[k], a2g);
        a2r = fmaf(ra[k], ra[k], a2r);
    }

    const float s    = stdp[0];
    const float ninv = -1.0f / (2.0f * s * s);
    const float k2   = ninv * 1.442695040888963f;   // * log2(e)

    const float* wTg = ws;
    const float* wTr = ws + D * O;
    const float* n2g = ws + 2 * D * O;
    const float* n2r = n2g + O;

    float* ob = out + (size_t)b * O * P + p;

    #pragma unroll 1   // 4 chunks of 16 channels; patches stay resident
    for (int o0 = 0; o0 < O; o0 += 16) {
        float dg[16], dr[16];
        #pragma unroll
        for (int j = 0; j < 16; ++j) { dg[j] = 0.f; dr[j] = 0.f; }

        #pragma unroll
        for (int k = 0; k < D; ++k) {
            const float g = ga[k];
            const float r = ra[k];
            const float* wg = wTg + k * O + o0;   // wave-uniform -> s_load
            const float* wr = wTr + k * O + o0;
            #pragma unroll
            for (int j = 0; j < 16; ++j) {
                dg[j] = fmaf(g, wg[j], dg[j]);
                dr[j] = fmaf(r, wr[j], dr[j]);
            }
        }

        #pragma unroll
        for (int j = 0; j < 16; ++j) {
            float d2g = fmaxf(fmaf(-2.f, dg[j], a2g + n2g[o0 + j]), 0.f);
            float d2r = fmaxf(fmaf(-2.f, dr[j], a2r + n2r[o0 + j]), 0.f);
            // dist^2 = d2g + d2r + 2*sqrt(d2g*d2r)
            float sq = __builtin_amdgcn_sqrtf(d2g * d2r);
            float t  = fmaf(2.f, sq, d2g + d2r);
            ob[(size_t)(o0 + j) * P] = __builtin_amdgcn_exp2f(k2 * t);
        }
    }
}

// Fallback (round-1 kernel, known-correct) in case ws_size is too small.
__global__ __launch_bounds__(256) void rbf_conv_fallback(
    const float* __restrict__ gin, const float* __restrict__ rin,
    const float* __restrict__ gw,  const float* __restrict__ rw,
    const float* __restrict__ stdp, float* __restrict__ out, int B)
{
    __shared__ float s_w2g[O], s_w2r[O];
    const int t = threadIdx.x;
    if (t < O) {
        float sg = 0.f, sr = 0.f;
        #pragma unroll
        for (int k = 0; k < D; ++k) {
            float a = gw[t * D + k]; sg = fmaf(a, a, sg);
            float b = rw[t * D + k]; sr = fmaf(b, b, sr);
        }
        s_w2g[t] = sg;
        s_w2r[t] = sr;
    }
    __syncthreads();

    const int idx = blockIdx.x * blockDim.x + t;
    if (idx >= B * P) return;
    const int b = idx / P;
    const int p = idx - b * P;
    const int y = p / OW;
    const int x = p - y * OW;

    const float* gb = gin + (b * H + y) * W + x;
    const float* rb = rin + (b * H + y) * W + x;
    float ga[D], ra[D];
    float a2g = 0.f, a2r = 0.f;
    #pragma unroll
    for (int i = 0; i < KH; ++i)
        #pragma unroll
        for (int j = 0; j < KW; ++j) {
            float g = gb[i * W + j]; ga[i * KW + j] = g; a2g = fmaf(g, g, a2g);
            float r = rb[i * W + j]; ra[i * KW + j] = r; a2r = fmaf(r, r, a2r);
        }

    const float s    = stdp[0];
    const float ninv = -1.0f / (2.0f * s * s);
    float* ob = out + (size_t)b * O * P + p;

    for (int o = 0; o < O; ++o) {
        float dg = 0.f, dr = 0.f;
        #pragma unroll
        for (int k = 0; k < D; ++k) {
            dg = fmaf(ga[k], gw[o * D + k], dg);
            dr = fmaf(ra[k], rw[o * D + k], dr);
        }
        float d2g = fmaxf(a2g + s_w2g[o] - 2.0f * dg, 0.f);
        float d2r = fmaxf(a2r + s_w2r[o] - 2.0f * dr, 0.f);
        float dist = __fsqrt_rn(d2g) + __fsqrt_rn(d2r);
        ob[(size_t)o * P] = __expf(ninv * dist * dist);
    }
}

extern "C" void kernel_launch(void* const* d_in, const int* in_sizes, int n_in,
                              void* d_out, int out_size, void* d_ws, size_t ws_size,
                              hipStream_t stream) {
    const float* gin  = (const float*)d_in[0];
    const float* rin  = (const float*)d_in[1];
    const float* gw   = (const float*)d_in[2];
    const float* rw   = (const float*)d_in[3];
    const float* stdp = (const float*)d_in[4];
    float* out = (float*)d_out;

    const int B = in_sizes[0] / (H * W);   // 32
    const int total = B * P;
    const int block = 256;
    const int grid  = (total + block - 1) / block;

    if (ws_size >= WS_FLOATS * sizeof(float) && d_ws != nullptr) {
        float* ws = (float*)d_ws;
        prep_weights<<<1, 64, 0, stream>>>(gw, rw, ws);
        rbf_main<<<grid, block, 0, stream>>>(gin, rin, ws, stdp, out, B);
    } else {
        rbf_conv_fallback<<<grid, block, 0, stream>>>(gin, rin, gw, rw, stdp, out, B);
    }
}

// Round 4
// 43.363 us; speedup vs baseline: 1.4587x; 1.4587x over previous
//
#include <hip/hip_runtime.h>

// B=32, C=1, H=W=112, O=64, KH=KW=5, stride=1 -> oh=ow=108
constexpr int KH = 5, KW = 5;
constexpr int O  = 64;
constexpr int D  = KH * KW;          // 25
constexpr int H  = 112, W = 112;
constexpr int OH = H - KH + 1;       // 108
constexpr int OW = W - KW + 1;       // 108
constexpr int P  = OH * OW;          // 11664 (divisible by 16)

typedef __attribute__((ext_vector_type(8))) short short8v;   // 8 bf16 (4 VGPRs)
typedef __attribute__((ext_vector_type(4))) float float4v;   // MFMA acc

// ws layout:
//   wfrag: short [4 Mt][2 img][2 split][64 lane][8 j]   = 8192 shorts = 16 KiB
//   n2i:   float [2 img][4 Mt][64 lane][4 reg]          = 2048 floats =  8 KiB
constexpr size_t WS_BYTES = 8192 * sizeof(short) + 2048 * sizeof(float);

__device__ inline unsigned short bf16_trunc(float f) {
    return (unsigned short)(__float_as_uint(f) >> 16);
}

__global__ void prep_weights_mfma(const float* __restrict__ gw,
                                  const float* __restrict__ rw,
                                  void* wsv) {
    short* wfrag = (short*)wsv;
    float* n2i   = (float*)((char*)wsv + 8192 * sizeof(short));
    const int t = threadIdx.x;
    if (t >= 64) return;
    const int hi = t >> 4, c = t & 15;

    // A-operand (weight) fragments, hi/lo split, k-slot (hi,j) <-> k=hi*8+j.
    for (int Mt = 0; Mt < 4; ++Mt) {
        for (int img = 0; img < 2; ++img) {
            const float* wt = img ? rw : gw;
            const int o = Mt * 16 + c;
            for (int j = 0; j < 8; ++j) {
                const int k = hi * 8 + j;
                const float w = (k < D) ? wt[o * D + k] : 0.f;
                const unsigned bits = __float_as_uint(w);
                const float hf = __uint_as_float(bits & 0xFFFF0000u);
                const float lf = w - hf;            // exact residual
                wfrag[(((Mt * 2 + img) * 2 + 0) * 64 + t) * 8 + j] = (short)(bits >> 16);
                wfrag[(((Mt * 2 + img) * 2 + 1) * 64 + t) * 8 + j] = (short)bf16_trunc(lf);
            }
        }
    }

    // acc init = -0.5 * ||w_o||^2 for o = Mt*16 + (lane>>4)*4 + reg.
    for (int img = 0; img < 2; ++img) {
        const float* wt = img ? rw : gw;
        float s2 = 0.f;
        for (int k = 0; k < D; ++k) s2 = fmaf(wt[t * D + k], wt[t * D + k], s2);
        const float init = -0.5f * s2;
        const int Mt = t >> 4, hio = (t >> 2) & 3, reg = t & 3;
        for (int c2 = 0; c2 < 16; ++c2)
            n2i[((img * 4 + Mt) * 64 + hio * 16 + c2) * 4 + reg] = init;
    }
}

__global__ __launch_bounds__(256, 3) void rbf_mfma(
    const float* __restrict__ gin, const float* __restrict__ rin,
    const void* __restrict__ wsv,  const float* __restrict__ stdp,
    float* __restrict__ out, int totalTiles, int tilesPerWave)
{
    const short*  wfrag = (const short*)wsv;
    const float*  n2i   = (const float*)((const char*)wsv + 8192 * sizeof(short));
    const int lane = threadIdx.x & 63;
    const int hi   = lane >> 4;
    const int c    = lane & 15;
    const int wid  = blockIdx.x * 4 + (threadIdx.x >> 6);

    // Persistent weight fragments: [Mt][img][split]
    short8v wf[4][2][2];
    #pragma unroll
    for (int Mt = 0; Mt < 4; ++Mt)
        #pragma unroll
        for (int img = 0; img < 2; ++img)
            #pragma unroll
            for (int sp = 0; sp < 2; ++sp)
                wf[Mt][img][sp] = *(const short8v*)(wfrag +
                    (((Mt * 2 + img) * 2 + sp) * 64 + lane) * 8);

    // Per-lane patch-element offsets for k = hi*8+j (invalid k -> 0, weight=0 there).
    int offs[8];
    #pragma unroll
    for (int j = 0; j < 8; ++j) {
        const int k  = hi * 8 + j;
        const int ki = k / 5, kj = k - ki * 5;
        offs[j] = (k < D) ? (ki * W + kj) : 0;
    }

    const float s  = stdp[0];
    const float k2 = -1.442695040888963f / (2.f * s * s);   // -log2(e)/(2s^2)

    for (int t = 0; t < tilesPerWave; ++t) {
        const int tile = wid * tilesPerWave + t;
        if (tile >= totalTiles) break;
        const int pg0 = tile * 16;
        const int b   = pg0 / P;           // uniform within wave (P % 16 == 0)
        const int p0  = pg0 - b * P;
        const int p   = p0 + c;            // this lane's pixel (B-operand column)
        const int y   = p / OW;
        const int x   = p - y * OW;
        const float* gbase = gin + (b * H + y) * W + x;
        const float* rbase = rin + (b * H + y) * W + x;

        short8v pf[2][2];                  // [img][split]
        float   a2[2];
        #pragma unroll
        for (int img = 0; img < 2; ++img) {
            const float* base = img ? rbase : gbase;
            float v[8];
            #pragma unroll
            for (int j = 0; j < 8; ++j) v[j] = base[offs[j]];

            // |a|^2: lanes hi<3 own k=hi*8..hi*8+7; hi==3 owns only k=24 (j==0).
            float full = 0.f;
            #pragma unroll
            for (int j = 0; j < 8; ++j) full = fmaf(v[j], v[j], full);
            float part = (hi == 3) ? v[0] * v[0] : full;
            part += __shfl_xor(part, 16);
            part += __shfl_xor(part, 32);
            a2[img] = part;

            // hi/lo bf16 split (truncation; lo captures residual exactly).
            short8v ph, pl;
            #pragma unroll
            for (int j = 0; j < 8; ++j) {
                const unsigned bits = __float_as_uint(v[j]);
                const float hf = __uint_as_float(bits & 0xFFFF0000u);
                ph[j] = (short)(bits >> 16);
                pl[j] = (short)bf16_trunc(v[j] - hf);
            }
            pf[img][0] = ph;
            pf[img][1] = pl;
        }

        // acc init = -n2/2; then acc += dot  =>  d2 = a2 - 2*acc.
        float4v acc[4][2];
        #pragma unroll
        for (int Mt = 0; Mt < 4; ++Mt)
            #pragma unroll
            for (int img = 0; img < 2; ++img)
                acc[Mt][img] = *(const float4v*)(n2i + ((img * 4 + Mt) * 64 + lane) * 4);

        #pragma unroll
        for (int Mt = 0; Mt < 4; ++Mt) {
            #pragma unroll
            for (int img = 0; img < 2; ++img) {
                acc[Mt][img] = __builtin_amdgcn_mfma_f32_16x16x32_bf16(
                    wf[Mt][img][0], pf[img][0], acc[Mt][img], 0, 0, 0);
                acc[Mt][img] = __builtin_amdgcn_mfma_f32_16x16x32_bf16(
                    wf[Mt][img][1], pf[img][0], acc[Mt][img], 0, 0, 0);
                acc[Mt][img] = __builtin_amdgcn_mfma_f32_16x16x32_bf16(
                    wf[Mt][img][0], pf[img][1], acc[Mt][img], 0, 0, 0);
            }
        }

        // Epilogue: D row = o-group (first operand), col = lane&15 = pixel.
        float* ob = out + (size_t)b * O * P + p0 + c;
        #pragma unroll
        for (int Mt = 0; Mt < 4; ++Mt) {
            #pragma unroll
            for (int reg = 0; reg < 4; ++reg) {
                float dg = fmaxf(fmaf(-2.f, acc[Mt][0][reg], a2[0]), 0.f);
                float dr = fmaxf(fmaf(-2.f, acc[Mt][1][reg], a2[1]), 0.f);
                float t2 = fmaf(2.f, __builtin_amdgcn_sqrtf(dg * dr), dg + dr);
                const int o = Mt * 16 + hi * 4 + reg;
                ob[(size_t)o * P] = __builtin_amdgcn_exp2f(k2 * t2);
            }
        }
    }
}

// Fallback (round-1/3 kernel, known-correct) if ws is too small.
__global__ __launch_bounds__(256) void rbf_conv_fallback(
    const float* __restrict__ gin, const float* __restrict__ rin,
    const float* __restrict__ gw,  const float* __restrict__ rw,
    const float* __restrict__ stdp, float* __restrict__ out, int B)
{
    __shared__ float s_w2g[O], s_w2r[O];
    const int t = threadIdx.x;
    if (t < O) {
        float sg = 0.f, sr = 0.f;
        #pragma unroll
        for (int k = 0; k < D; ++k) {
            float a = gw[t * D + k]; sg = fmaf(a, a, sg);
            float b = rw[t * D + k]; sr = fmaf(b, b, sr);
        }
        s_w2g[t] = sg;
        s_w2r[t] = sr;
    }
    __syncthreads();

    const int idx = blockIdx.x * blockDim.x + t;
    if (idx >= B * P) return;
    const int b = idx / P;
    const int p = idx - b * P;
    const int y = p / OW;
    const int x = p - y * OW;

    const float* gb = gin + (b * H + y) * W + x;
    const float* rb = rin + (b * H + y) * W + x;
    float ga[D], ra[D];
    float a2g = 0.f, a2r = 0.f;
    #pragma unroll
    for (int i = 0; i < KH; ++i)
        #pragma unroll
        for (int j = 0; j < KW; ++j) {
            float g = gb[i * W + j]; ga[i * KW + j] = g; a2g = fmaf(g, g, a2g);
            float r = rb[i * W + j]; ra[i * KW + j] = r; a2r = fmaf(r, r, a2r);
        }

    const float s    = stdp[0];
    const float ninv = -1.0f / (2.0f * s * s);
    float* ob = out + (size_t)b * O * P + p;

    for (int o = 0; o < O; ++o) {
        float dg = 0.f, dr = 0.f;
        #pragma unroll
        for (int k = 0; k < D; ++k) {
            dg = fmaf(ga[k], gw[o * D + k], dg);
            dr = fmaf(ra[k], rw[o * D + k], dr);
        }
        float d2g = fmaxf(a2g + s_w2g[o] - 2.0f * dg, 0.f);
        float d2r = fmaxf(a2r + s_w2r[o] - 2.0f * dr, 0.f);
        float dist = __fsqrt_rn(d2g) + __fsqrt_rn(d2r);
        ob[(size_t)o * P] = __expf(ninv * dist * dist);
    }
}

extern "C" void kernel_launch(void* const* d_in, const int* in_sizes, int n_in,
                              void* d_out, int out_size, void* d_ws, size_t ws_size,
                              hipStream_t stream) {
    const float* gin  = (const float*)d_in[0];
    const float* rin  = (const float*)d_in[1];
    const float* gw   = (const float*)d_in[2];
    const float* rw   = (const float*)d_in[3];
    const float* stdp = (const float*)d_in[4];
    float* out = (float*)d_out;

    const int B = in_sizes[0] / (H * W);   // 32

    if (ws_size >= WS_BYTES && d_ws != nullptr && (B * P) % 16 == 0) {
        prep_weights_mfma<<<1, 64, 0, stream>>>(gw, rw, d_ws);
        const int totalTiles   = B * P / 16;          // 23328
        const int tilesPerWave = 8;
        const int waves  = (totalTiles + tilesPerWave - 1) / tilesPerWave;  // 2916
        const int blocks = (waves + 3) / 4;                                  // 729
        rbf_mfma<<<blocks, 256, 0, stream>>>(gin, rin, d_ws, stdp, out,
                                             totalTiles, tilesPerWave);
    } else {
        const int total = B * P;
        const int block = 256;
        const int grid  = (total + block - 1) / block;
        rbf_conv_fallback<<<grid, block, 0, stream>>>(gin, rin, gw, rw, stdp, out, B);
    }
}

// Round 5
// 34.982 us; speedup vs baseline: 1.8082x; 1.2396x over previous
//
#include <hip/hip_runtime.h>

// B=32, C=1, H=W=112, O=64, KH=KW=5, stride=1 -> oh=ow=108
constexpr int KH = 5, KW = 5;
constexpr int O  = 64;
constexpr int D  = KH * KW;          // 25
constexpr int H  = 112, W = 112;
constexpr int OH = H - KH + 1;       // 108
constexpr int OW = W - KW + 1;       // 108
constexpr int P  = OH * OW;          // 11664 (divisible by 16)

typedef __attribute__((ext_vector_type(8))) short short8v;   // 8 bf16 (4 VGPRs)
typedef __attribute__((ext_vector_type(4))) float float4v;   // MFMA acc

// ws layout: wfrag short [4 Mt][2 img][2 split][64 lane][8 j] = 8192 shorts.
// k-slot map: k = (lane>>4)*8 + j. Slots k<25: weights. Slot k==25 carries
// -0.5*||w_o||^2 (hi + residual-lo); the PATCH operand is forced to 1.0 (hi)
// and 0.0 (lo) at that slot, so MFMA from acc=0 yields dot - 0.5*||w||^2.
constexpr int    WF_SHORTS = 4 * 2 * 2 * 64 * 8;       // 8192
constexpr size_t WS_BYTES  = WF_SHORTS * sizeof(short); // 16 KiB

__global__ void prep_weights_mfma(const float* __restrict__ gw,
                                  const float* __restrict__ rw,
                                  void* wsv) {
    short* wfrag = (short*)wsv;
    const int t = threadIdx.x;                 // 0..255
    // 1024 units of (cfg = ((Mt*2+img)*2+sp), lane); 4 per thread.
    for (int u = t; u < 1024; u += 256) {
        const int lane = u & 63;
        const int cfg  = u >> 6;               // 0..15
        const int sp   = cfg & 1;
        const int img  = (cfg >> 1) & 1;
        const int Mt   = cfg >> 2;
        const int hi   = lane >> 4, c = lane & 15;
        const float* wt = img ? rw : gw;
        const int o = Mt * 16 + c;
        short8v v;
        #pragma unroll
        for (int j = 0; j < 8; ++j) {
            const int k = hi * 8 + j;
            float w;
            if (k < D) {
                w = wt[o * D + k];
            } else if (k == D) {               // homogeneous slot: -0.5*||w||^2
                float s2 = 0.f;
                for (int kk = 0; kk < D; ++kk) {
                    float x = wt[o * D + kk];
                    s2 = fmaf(x, x, s2);
                }
                w = -0.5f * s2;
            } else {
                w = 0.f;
            }
            const unsigned bits = __float_as_uint(w);
            if (sp == 0) {
                v[j] = (short)(bits >> 16);
            } else {
                const float hf = __uint_as_float(bits & 0xFFFF0000u);
                v[j] = (short)(__float_as_uint(w - hf) >> 16);
            }
        }
        *(short8v*)(wfrag + (cfg * 64 + lane) * 8) = v;
    }
}

__global__ __launch_bounds__(256, 3) void rbf_mfma(
    const float* __restrict__ gin, const float* __restrict__ rin,
    const void* __restrict__ wsv,  const float* __restrict__ stdp,
    float* __restrict__ out)
{
    const short* wfrag = (const short*)wsv;
    const int lane = threadIdx.x & 63;
    const int hi   = lane >> 4;
    const int c    = lane & 15;
    const int wid  = blockIdx.x * 4 + (threadIdx.x >> 6);
    const int tile0 = wid * 8;                 // 8 tiles per wave, exact cover

    // Persistent weight fragments: [Mt][img][split]  (64 VGPRs)
    short8v wf[4][2][2];
    #pragma unroll
    for (int Mt = 0; Mt < 4; ++Mt)
        #pragma unroll
        for (int img = 0; img < 2; ++img)
            #pragma unroll
            for (int sp = 0; sp < 2; ++sp)
                wf[Mt][img][sp] = *(const short8v*)(wfrag +
                    (((Mt * 2 + img) * 2 + sp) * 64 + lane) * 8);

    // Per-lane patch-element offsets for k = hi*8+j (k>=25 -> dummy 0).
    int offs[8];
    #pragma unroll
    for (int j = 0; j < 8; ++j) {
        const int k  = hi * 8 + j;
        const int ki = k / 5, kj = k - ki * 5;
        offs[j] = (k < D) ? (ki * W + kj) : 0;
    }

    const float s  = stdp[0];
    const float k2 = -1.442695040888963f / (2.f * s * s);   // -log2(e)/(2s^2)

    auto addr = [&](int t, const float*& gb, const float*& rb, float*& ob) {
        const unsigned pg0 = (unsigned)(tile0 + t) * 16u;
        const unsigned b   = pg0 / (unsigned)P;
        const unsigned p0  = pg0 - b * (unsigned)P;
        const unsigned p   = p0 + (unsigned)c;
        const unsigned y   = p / (unsigned)OW;
        const unsigned x   = p - y * (unsigned)OW;
        const int ibase = (int)((b * H + y) * W + x);
        gb = gin + ibase;
        rb = rin + ibase;
        ob = out + (size_t)b * O * P + p0 + c;
    };

    auto load8 = [&](float (&v)[8], const float* base) {
        #pragma unroll
        for (int j = 0; j < 8; ++j) v[j] = base[offs[j]];
    };

    auto split_one = [&](const float (&v)[8], short8v& ph, short8v& pl, float& a2o) {
        float full = 0.f;
        #pragma unroll
        for (int j = 0; j < 8; ++j) full = fmaf(v[j], v[j], full);
        float part = (hi == 3) ? v[0] * v[0] : full;   // hi==3 owns only k=24
        part += __shfl_xor(part, 16);
        part += __shfl_xor(part, 32);
        a2o = part;
        #pragma unroll
        for (int j = 0; j < 8; ++j) {
            const unsigned bits = __float_as_uint(v[j]);
            const float hf = __uint_as_float(bits & 0xFFFF0000u);
            ph[j] = (short)(bits >> 16);
            pl[j] = (short)(__float_as_uint(v[j] - hf) >> 16);
        }
        if (hi == 3) { ph[1] = (short)0x3F80; pl[1] = (short)0; }  // slot k=25 := 1.0
    };

    auto process = [&](float (&vg)[8], float (&vr)[8], float* ob) {
        short8v pf[2][2];
        float a2v[2];
        split_one(vg, pf[0][0], pf[0][1], a2v[0]);
        split_one(vr, pf[1][0], pf[1][1], a2v[1]);

        const float4v z4 = {0.f, 0.f, 0.f, 0.f};
        float4v acc[4][2];
        #pragma unroll
        for (int Mt = 0; Mt < 4; ++Mt) {
            #pragma unroll
            for (int img = 0; img < 2; ++img) {
                float4v a0 = __builtin_amdgcn_mfma_f32_16x16x32_bf16(
                    wf[Mt][img][0], pf[img][0], z4, 0, 0, 0);
                a0 = __builtin_amdgcn_mfma_f32_16x16x32_bf16(
                    wf[Mt][img][1], pf[img][0], a0, 0, 0, 0);
                acc[Mt][img] = __builtin_amdgcn_mfma_f32_16x16x32_bf16(
                    wf[Mt][img][0], pf[img][1], a0, 0, 0, 0);
            }
        }

        #pragma unroll
        for (int Mt = 0; Mt < 4; ++Mt) {
            #pragma unroll
            for (int reg = 0; reg < 4; ++reg) {
                float dg = fmaxf(fmaf(-2.f, acc[Mt][0][reg], a2v[0]), 0.f);
                float dr = fmaxf(fmaf(-2.f, acc[Mt][1][reg], a2v[1]), 0.f);
                float t2 = fmaf(2.f, __builtin_amdgcn_sqrtf(dg * dr), dg + dr);
                ob[(size_t)(Mt * 16 + hi * 4 + reg) * P] =
                    __builtin_amdgcn_exp2f(k2 * t2);
            }
        }
    };

    // 2-deep software pipeline over 8 tiles (ping/pong, all names static).
    const float *gbA, *rbA, *gbB, *rbB;
    float *obA, *obB;
    float vgA[8], vrA[8], vgB[8], vrB[8];

    addr(0, gbA, rbA, obA);
    load8(vgA, gbA); load8(vrA, rbA);

    #pragma unroll 1
    for (int it = 0; it < 4; ++it) {
        addr(2 * it + 1, gbB, rbB, obB);
        load8(vgB, gbB); load8(vrB, rbB);
        process(vgA, vrA, obA);
        if (it < 3) {
            addr(2 * it + 2, gbA, rbA, obA);
            load8(vgA, gbA); load8(vrA, rbA);
        }
        process(vgB, vrB, obB);
    }
}

// Fallback (round-1 kernel, known-correct) if ws is too small.
__global__ __launch_bounds__(256) void rbf_conv_fallback(
    const float* __restrict__ gin, const float* __restrict__ rin,
    const float* __restrict__ gw,  const float* __restrict__ rw,
    const float* __restrict__ stdp, float* __restrict__ out, int B)
{
    __shared__ float s_w2g[O], s_w2r[O];
    const int t = threadIdx.x;
    if (t < O) {
        float sg = 0.f, sr = 0.f;
        #pragma unroll
        for (int k = 0; k < D; ++k) {
            float a = gw[t * D + k]; sg = fmaf(a, a, sg);
            float b = rw[t * D + k]; sr = fmaf(b, b, sr);
        }
        s_w2g[t] = sg;
        s_w2r[t] = sr;
    }
    __syncthreads();

    const int idx = blockIdx.x * blockDim.x + t;
    if (idx >= B * P) return;
    const int b = idx / P;
    const int p = idx - b * P;
    const int y = p / OW;
    const int x = p - y * OW;

    const float* gb = gin + (b * H + y) * W + x;
    const float* rb = rin + (b * H + y) * W + x;
    float ga[D], ra[D];
    float a2g = 0.f, a2r = 0.f;
    #pragma unroll
    for (int i = 0; i < KH; ++i)
        #pragma unroll
        for (int j = 0; j < KW; ++j) {
            float g = gb[i * W + j]; ga[i * KW + j] = g; a2g = fmaf(g, g, a2g);
            float r = rb[i * W + j]; ra[i * KW + j] = r; a2r = fmaf(r, r, a2r);
        }

    const float s    = stdp[0];
    const float ninv = -1.0f / (2.0f * s * s);
    float* ob = out + (size_t)b * O * P + p;

    for (int o = 0; o < O; ++o) {
        float dg = 0.f, dr = 0.f;
        #pragma unroll
        for (int k = 0; k < D; ++k) {
            dg = fmaf(ga[k], gw[o * D + k], dg);
            dr = fmaf(ra[k], rw[o * D + k], dr);
        }
        float d2g = fmaxf(a2g + s_w2g[o] - 2.0f * dg, 0.f);
        float d2r = fmaxf(a2r + s_w2r[o] - 2.0f * dr, 0.f);
        float dist = __fsqrt_rn(d2g) + __fsqrt_rn(d2r);
        ob[(size_t)o * P] = __expf(ninv * dist * dist);
    }
}

extern "C" void kernel_launch(void* const* d_in, const int* in_sizes, int n_in,
                              void* d_out, int out_size, void* d_ws, size_t ws_size,
                              hipStream_t stream) {
    const float* gin  = (const float*)d_in[0];
    const float* rin  = (const float*)d_in[1];
    const float* gw   = (const float*)d_in[2];
    const float* rw   = (const float*)d_in[3];
    const float* stdp = (const float*)d_in[4];
    float* out = (float*)d_out;

    const int B = in_sizes[0] / (H * W);   // 32

    const int totalTiles = B * P / 16;     // 23328
    if (ws_size >= WS_BYTES && d_ws != nullptr &&
        (B * P) % 16 == 0 && totalTiles % 8 == 0) {
        prep_weights_mfma<<<1, 256, 0, stream>>>(gw, rw, d_ws);
        const int waves  = totalTiles / 8;          // 2916
        const int blocks = (waves + 3) / 4;         // 729
        rbf_mfma<<<blocks, 256, 0, stream>>>(gin, rin, d_ws, stdp, out);
    } else {
        const int total = B * P;
        const int block = 256;
        const int grid  = (total + block - 1) / block;
        rbf_conv_fallback<<<grid, block, 0, stream>>>(gin, rin, gw, rw, stdp, out, B);
    }
}